// Round 2
// baseline (450.104 us; speedup 1.0000x reference)
//
#include <hip/hip_runtime.h>
#include <utility>

typedef float f32x2 __attribute__((ext_vector_type(2)));

#define LOG2E 1.44269504088896340736f

__device__ __forceinline__ float rcp_fast(float x) { return __builtin_amdgcn_rcpf(x); }

__device__ __forceinline__ float sigmoid_fast(float x) {
    // 1/(1+exp(-x)); exp2 overflow -> inf -> rcp -> 0 (correct limit), no NaN
    return rcp_fast(1.0f + __builtin_amdgcn_exp2f(-LOG2E * x));
}

__device__ __forceinline__ float tanh_fast(float x) {
    // overflow-safe: t = exp2(-2*log2e*|x|) in (0,1]
    float a = __builtin_fabsf(x);
    float t = __builtin_amdgcn_exp2f(-2.0f * LOG2E * a);
    float r = (1.0f - t) * rcp_fast(1.0f + t);
    return __builtin_copysignf(r, x);
}

// DPP row_ror:R — rotation within 16-lane rows (gfx9 row = 16 lanes).
// All rotations read the ORIGINAL register -> no serial dependency chain.
template <int R>
__device__ __forceinline__ int ror16_i(int v) {
    if constexpr (R == 0) {
        return v;
    } else {
        return __builtin_amdgcn_update_dpp(v, v, 0x120 + R, 0xF, 0xF, false);
    }
}
template <int R>
__device__ __forceinline__ float ror16(float v) {
    return __builtin_bit_cast(float, ror16_i<R>(__builtin_bit_cast(int, v)));
}

template <typename F, int... Rs>
__device__ __forceinline__ void sf_impl(F&& f, std::integer_sequence<int, Rs...>) {
    (f(std::integral_constant<int, Rs>{}), ...);
}
template <int N, typename F>
__device__ __forceinline__ void static_for(F&& f) {
    sf_impl(f, std::make_integer_sequence<int, N>{});
}

// One wave = 4 batch elements (16 lanes each, lane j = hidden index).
// Lane j register-resident weights, stored in ROTATION ORDER (index r, not k):
//   Wg[r]     = ln_gamma-folded W_in[j][kr[r]]
//   Wpk[q][r] = (W_ih[q*16+j][kr[r]], W_hh[q*16+j][kr[r]])  -> v_pk_fma_f32
//   Wo[r]     = W_out[j][kr[r]] (j<12)
// where kr[r] = source lane of row_ror:r, measured at runtime (self-calibrating,
// immune to ROR direction convention).  No LDS, no barriers anywhere.
__global__ __launch_bounds__(64, 2) void vm_kernel(
    const float* __restrict__ init_state,  // (B,1,12)
    const float* __restrict__ commands,    // (B,T,4)
    const float* __restrict__ ln_g,        // (16)
    const float* __restrict__ ln_b,        // (16)
    const float* __restrict__ W_in,        // (16,16)
    const float* __restrict__ b_in,        // (16)
    const float* __restrict__ W_ih,        // (64,16)
    const float* __restrict__ W_hh,        // (64,16)
    const float* __restrict__ b_ih,        // (64)
    const float* __restrict__ b_hh,        // (64)
    const float* __restrict__ W_out,       // (12,16)
    const float* __restrict__ b_out,       // (12)
    float* __restrict__ out,               // (B,T,12)
    int B, int T)
{
    const int lane = threadIdx.x;
    const int j = lane & 15;
    const int b = blockIdx.x * 4 + (lane >> 4);

    // ---- calibrate rotation source indices ----
    int kr[16];
    kr[0] = j;
    static_for<15>([&](auto rc) {
        constexpr int R = decltype(rc)::value + 1;
        kr[R] = ror16_i<R>(j);
    });

    // ---- preamble: weights into registers in rotation order ----
    float Wg[16];
    float wbeta, sWg = 0.0f;
    {
        const float* wr = W_in + j * 16;
        float bsum = b_in[j];
#pragma unroll
        for (int r = 0; r < 16; ++r) {
            int k = kr[r];
            float w = wr[k] * ln_g[k];
            Wg[r] = w;
            sWg += w;
        }
#pragma unroll
        for (int k = 0; k < 16; ++k) bsum += wr[k] * ln_b[k];
        wbeta = bsum;
    }

    f32x2 Wpk[4][16];
    float gb[4];
#pragma unroll
    for (int q = 0; q < 4; ++q) {
        const float* rx = W_ih + (q * 16 + j) * 16;
        const float* rh = W_hh + (q * 16 + j) * 16;
#pragma unroll
        for (int r = 0; r < 16; ++r) {
            int k = kr[r];
            f32x2 w;
            w[0] = rx[k];
            w[1] = rh[k];
            Wpk[q][r] = w;
        }
        gb[q] = b_ih[q * 16 + j] + b_hh[q * 16 + j];
    }

    float Wo[16];
    float bo = 0.0f;
#pragma unroll
    for (int r = 0; r < 16; ++r) Wo[r] = 0.0f;
    if (j < 12) {
        const float* ro = W_out + j * 16;
#pragma unroll
        for (int r = 0; r < 16; ++r) Wo[r] = ro[kr[r]];
        bo = b_out[j];
    }

    // sincos partner lane (pairs (1,2),(3,4),(5,6)); resolve ROR direction per lane
    int pj = j;
    if (j >= 1 && j <= 6) pj = ((j - 1) ^ 1) + 1;
    const bool donorm = (j >= 1 && j <= 6);
    const bool use_r1 = (kr[1] == pj);   // does row_ror:1 deliver the partner?

    // ---- per-batch recurrent state ----
    const bool is_state = (j < 12);
    float st = is_state ? init_state[b * 12 + j] : 0.0f;
    float h = 0.0f, c = 0.0f;

    const float* cmd_ptr = commands + (size_t)b * T * 4 + (j - 12);
    float cmd = (j >= 12) ? cmd_ptr[0] : 0.0f;

    float* out_ptr = out + (size_t)b * T * 12 + j;

    for (int t = 0; t < T; ++t) {
        float x = is_state ? st : cmd;

        // software-prefetch next step's command (independent of this step's math)
        int tn = (t + 1 < T) ? (t + 1) : t;
        float cmd_next = (j >= 12) ? cmd_ptr[(size_t)tn * 4] : 0.0f;

        // ---- LN stats + gamma-folded W_in dot, systolic over rotations ----
        float sum = x;
        float sumsq = x * x;
        float dot = Wg[0] * x;
        static_for<15>([&](auto rc) {
            constexpr int R = decltype(rc)::value + 1;
            float xr = ror16<R>(x);
            sum += xr;
            sumsq = __builtin_fmaf(xr, xr, sumsq);
            dot = __builtin_fmaf(Wg[R], xr, dot);
        });
        float mu = sum * 0.0625f;
        float var = __builtin_fmaf(sumsq, 0.0625f, -mu * mu);
        float inv = __builtin_amdgcn_rsqf(var + 1e-5f);
        float xh = __builtin_fmaf(dot - mu * sWg, inv, wbeta);

        // ---- gates: pk_fma over packed (xh_k, h_k) rotations ----
        f32x2 v0;
        v0[0] = xh;
        v0[1] = h;
        f32x2 a0 = Wpk[0][0] * v0;
        f32x2 a1 = Wpk[1][0] * v0;
        f32x2 a2 = Wpk[2][0] * v0;
        f32x2 a3 = Wpk[3][0] * v0;
        static_for<15>([&](auto rc) {
            constexpr int R = decltype(rc)::value + 1;
            f32x2 v;
            v[0] = ror16<R>(xh);
            v[1] = ror16<R>(h);
            a0 += Wpk[0][R] * v;
            a1 += Wpk[1][R] * v;
            a2 += Wpk[2][R] * v;
            a3 += Wpk[3][R] * v;
        });
        float gi = a0[0] + a0[1] + gb[0];
        float gf = a1[0] + a1[1] + gb[1];
        float gg = a2[0] + a2[1] + gb[2];
        float go = a3[0] + a3[1] + gb[3];

        float iv = sigmoid_fast(gi);
        float fv = sigmoid_fast(gf);
        float gv = tanh_fast(gg);
        float ov = sigmoid_fast(go);
        c = __builtin_fmaf(fv, c, iv * gv);
        h = ov * tanh_fast(c);

        // ---- W_out dot, systolic ----
        float o = Wo[0] * h;
        static_for<15>([&](auto rc) {
            constexpr int R = decltype(rc)::value + 1;
            o = __builtin_fmaf(Wo[R], ror16<R>(h), o);
        });
        if (is_state) st += o + bo;

        // ---- sincos pair renorm via DPP neighbor exchange ----
        float p1 = ror16<1>(st);
        float p15 = ror16<15>(st);
        float pv = use_r1 ? p1 : p15;
        if (donorm) {
            float n = __builtin_amdgcn_sqrtf(__builtin_fmaf(st, st, pv * pv)) + 1e-8f;
            st *= rcp_fast(n);
        }

        if (is_state) out_ptr[0] = st;
        out_ptr += 12;
        cmd = cmd_next;
    }
}

extern "C" void kernel_launch(void* const* d_in, const int* in_sizes, int n_in,
                              void* d_out, int out_size, void* d_ws, size_t ws_size,
                              hipStream_t stream) {
    const float* init_state = (const float*)d_in[0];
    const float* commands   = (const float*)d_in[1];
    const float* ln_g       = (const float*)d_in[2];
    const float* ln_b       = (const float*)d_in[3];
    const float* W_in       = (const float*)d_in[4];
    const float* b_in       = (const float*)d_in[5];
    const float* W_ih       = (const float*)d_in[6];
    const float* W_hh       = (const float*)d_in[7];
    const float* b_ih       = (const float*)d_in[8];
    const float* b_hh       = (const float*)d_in[9];
    const float* W_out      = (const float*)d_in[10];
    const float* b_out      = (const float*)d_in[11];

    int B = in_sizes[0] / 12;           // 8192
    int T = in_sizes[1] / (B * 4);      // 256

    int blocks = B / 4;                 // 4 batch elements per 64-thread block
    vm_kernel<<<blocks, 64, 0, stream>>>(init_state, commands, ln_g, ln_b,
                                         W_in, b_in, W_ih, W_hh, b_ih, b_hh,
                                         W_out, b_out, (float*)d_out, B, T);
}

// Round 3
// 427.653 us; speedup vs baseline: 1.0525x; 1.0525x over previous
//
#include <hip/hip_runtime.h>

typedef float f32x2 __attribute__((ext_vector_type(2)));
typedef float f32x4 __attribute__((ext_vector_type(4)));

#define LOG2E 1.44269504088896340736f

__device__ __forceinline__ float rcp_fast(float x) { return __builtin_amdgcn_rcpf(x); }
__device__ __forceinline__ f32x2 mk2(float a, float b) { f32x2 v; v[0] = a; v[1] = b; return v; }
__device__ __forceinline__ f32x2 splat2(float a) { return mk2(a, a); }

__device__ __forceinline__ float sigmoid_fast(float x) {
    return rcp_fast(1.0f + __builtin_amdgcn_exp2f(-LOG2E * x));
}
__device__ __forceinline__ float tanh_fast(float x) {
    float a = __builtin_fabsf(x);
    float t = __builtin_amdgcn_exp2f(-2.0f * LOG2E * a);
    float r = (1.0f - t) * rcp_fast(1.0f + t);
    return __builtin_copysignf(r, x);
}

// swap with lane^16 (BitMode: xor=0x10, and=0x1F) — works within each 32-lane group
__device__ __forceinline__ float swz_xor16(float v) {
    return __builtin_bit_cast(float, __builtin_amdgcn_ds_swizzle(__builtin_bit_cast(int, v), 0x401F));
}

// DPP rotate within 16-lane rows (verified in R2)
template <int R>
__device__ __forceinline__ int ror16_i(int v) {
    if constexpr (R == 0) return v;
    else return __builtin_amdgcn_update_dpp(v, v, 0x120 + R, 0xF, 0xF, false);
}
template <int R>
__device__ __forceinline__ float ror16(float v) {
    return __builtin_bit_cast(float, ror16_i<R>(__builtin_bit_cast(int, v)));
}

__device__ __forceinline__ void quads_to_pairs(const float* p, f32x2* dst) {
    const f32x4* q4 = (const f32x4*)p;
    f32x4 a = q4[0], b = q4[1], c = q4[2], d = q4[3];
    dst[0] = __builtin_shufflevector(a, a, 0, 1);
    dst[1] = __builtin_shufflevector(a, a, 2, 3);
    dst[2] = __builtin_shufflevector(b, b, 0, 1);
    dst[3] = __builtin_shufflevector(b, b, 2, 3);
    dst[4] = __builtin_shufflevector(c, c, 0, 1);
    dst[5] = __builtin_shufflevector(c, c, 2, 3);
    dst[6] = __builtin_shufflevector(d, d, 0, 1);
    dst[7] = __builtin_shufflevector(d, d, 2, 3);
}

// One wave = 2 batch elements (32 lanes each). Lane (g=lane>>5, u=(lane>>4)&1,
// j=lane&15). Lane handles gate rows Q0=(2u)*16+j, Q1=Q0+16 with FUSED weights:
//   gates_Q = inv*(A[Q]·x_raw - mu*u[Q]) + d[Q] + W_hh[Q]·h
// where A = W_ih·(W_in·diag(gamma)) etc. — no xh broadcast, 2 LDS round trips
// per step (x and h), gate (i,f)/(g,o) exchange via one ds_swizzle xor16.
__global__ __launch_bounds__(64, 4) void vm_kernel(
    const float* __restrict__ init_state,  // (B,1,12)
    const float* __restrict__ commands,    // (B,T,4)
    const float* __restrict__ ln_g,        // (16)
    const float* __restrict__ ln_b,        // (16)
    const float* __restrict__ W_in,        // (16,16)
    const float* __restrict__ b_in,        // (16)
    const float* __restrict__ W_ih,        // (64,16)
    const float* __restrict__ W_hh,        // (64,16)
    const float* __restrict__ b_ih,        // (64)
    const float* __restrict__ b_hh,        // (64)
    const float* __restrict__ W_out,       // (12,16)
    const float* __restrict__ b_out,       // (12)
    float* __restrict__ out,               // (B,T,12)
    int B, int T)
{
    const int lane = threadIdx.x;
    const int j = lane & 15;
    const int u = (lane >> 4) & 1;
    const int g = lane >> 5;
    const int b = blockIdx.x * 2 + g;

    __shared__ __align__(16) float sh_x[2][16];
    __shared__ __align__(16) float sh_h[2][16];
    __shared__ __align__(16) float sh_wo[16][20];  // padded rows, 16B-aligned

    // ---- stage W_out rows into LDS (zeros for j>=12) ----
    if (lane < 16) {
#pragma unroll
        for (int k = 0; k < 16; ++k)
            sh_wo[lane][k] = (lane < 12) ? W_out[lane * 16 + k] : 0.0f;
    }

    // ---- preamble: fused weight computation ----
    const int Q0 = (2 * u) * 16 + j;   // u=0 -> gates i,f ; u=1 -> gates g,o
    const int Q1 = Q0 + 16;

    f32x2 A0[8], A1[8];
#pragma unroll
    for (int k = 0; k < 8; ++k) { A0[k] = splat2(0.0f); A1[k] = splat2(0.0f); }
    float uu0 = 0.0f, uu1 = 0.0f;
    float d0 = b_ih[Q0] + b_hh[Q0];
    float d1 = b_ih[Q1] + b_hh[Q1];

    for (int m = 0; m < 16; ++m) {
        float wi0 = W_ih[Q0 * 16 + m];
        float wi1 = W_ih[Q1 * 16 + m];
        const float* wr = W_in + m * 16;
        float sW = 0.0f, wb = b_in[m];
#pragma unroll
        for (int k = 0; k < 8; ++k) {
            float g0 = wr[2 * k] * ln_g[2 * k];
            float g1 = wr[2 * k + 1] * ln_g[2 * k + 1];
            f32x2 wg = mk2(g0, g1);
            A0[k] += splat2(wi0) * wg;
            A1[k] += splat2(wi1) * wg;
            sW += g0 + g1;
            wb += wr[2 * k] * ln_b[2 * k] + wr[2 * k + 1] * ln_b[2 * k + 1];
        }
        uu0 += wi0 * sW; uu1 += wi1 * sW;
        d0 += wi0 * wb;  d1 += wi1 * wb;
    }

    f32x2 Wh0[8], Wh1[8];
    {
        const float* r0 = W_hh + Q0 * 16;
        const float* r1 = W_hh + Q1 * 16;
#pragma unroll
        for (int k = 0; k < 8; ++k) {
            Wh0[k] = mk2(r0[2 * k], r0[2 * k + 1]);
            Wh1[k] = mk2(r1[2 * k], r1[2 * k + 1]);
        }
    }

    const float bo = (j < 12) ? b_out[j] : 0.0f;

    // ---- recurrent state (replicated in all lanes of a batch group) ----
    float st = (j < 12) ? init_state[b * 12 + j] : 0.0f;
    float c = 0.0f, h = 0.0f;
    f32x2 hp[8];
#pragma unroll
    for (int k = 0; k < 8; ++k) hp[k] = splat2(0.0f);

    const float* cmd_ptr = commands + (size_t)b * T * 4 + (j - 12);
    float cmd = (j >= 12) ? cmd_ptr[0] : 0.0f;
    float* out_ptr = out + (size_t)b * T * 12 + j;

    // sincos partner (pairs (1,2),(3,4),(5,6)); DPP direction self-calibrated
    int pj = j;
    if (j >= 1 && j <= 6) pj = ((j - 1) ^ 1) + 1;
    const bool donorm = (j >= 1 && j <= 6);
    const bool use_r1 = (ror16_i<1>(j) == pj);

    __syncthreads();

    for (int t = 0; t < T; ++t) {
        float x = (j < 12) ? st : cmd;
        if (u == 0) sh_x[g][j] = x;

        int tn = (t + 1 < T) ? (t + 1) : t;
        float cmd_next = (j >= 12) ? cmd_ptr[(size_t)tn * 4] : 0.0f;

        __syncthreads();

        f32x2 xp[8];
        quads_to_pairs(&sh_x[g][0], xp);

        // LN stats on raw x
        f32x2 s2 = ((xp[0] + xp[1]) + (xp[2] + xp[3])) + ((xp[4] + xp[5]) + (xp[6] + xp[7]));
        float sum = s2[0] + s2[1];
        f32x2 q2 = xp[0] * xp[0];
#pragma unroll
        for (int k = 1; k < 8; ++k) q2 += xp[k] * xp[k];
        float sumsq = q2[0] + q2[1];
        float mu = sum * 0.0625f;
        float var = __builtin_fmaf(sumsq, 0.0625f, -mu * mu);
        float inv = __builtin_amdgcn_rsqf(var + 1e-5f);

        // fused gate dots: A·x and W_hh·h
        f32x2 a0 = A0[0] * xp[0], a1 = A1[0] * xp[0];
        f32x2 h0 = Wh0[0] * hp[0], h1 = Wh1[0] * hp[0];
#pragma unroll
        for (int k = 1; k < 8; ++k) {
            a0 += A0[k] * xp[k];
            a1 += A1[k] * xp[k];
            h0 += Wh0[k] * hp[k];
            h1 += Wh1[k] * hp[k];
        }
        float gx0 = a0[0] + a0[1], gx1 = a1[0] + a1[1];
        float gh0 = h0[0] + h0[1], gh1 = h1[0] + h1[1];

        float G0 = __builtin_fmaf(__builtin_fmaf(-mu, uu0, gx0), inv, d0 + gh0);
        float G1 = __builtin_fmaf(__builtin_fmaf(-mu, uu1, gx1), inv, d1 + gh1);

        // exchange with partner half (u^1): get the other two gates
        float e0 = swz_xor16(G0);
        float e1 = swz_xor16(G1);
        float gi = u ? e0 : G0;
        float gf = u ? e1 : G1;
        float gg = u ? G0 : e0;
        float go = u ? G1 : e1;

        float iv = sigmoid_fast(gi);
        float fv = sigmoid_fast(gf);
        float gv = tanh_fast(gg);
        float ov = sigmoid_fast(go);
        c = __builtin_fmaf(fv, c, iv * gv);
        h = ov * tanh_fast(c);

        if (u == 0) sh_h[g][j] = h;
        __syncthreads();

        quads_to_pairs(&sh_h[g][0], hp);   // persists into next step's W_hh·h

        f32x2 wop[8];
        quads_to_pairs(&sh_wo[j][0], wop);
        f32x2 oa = wop[0] * hp[0];
#pragma unroll
        for (int k = 1; k < 8; ++k) oa += wop[k] * hp[k];
        float o = oa[0] + oa[1];

        st += o + bo;   // j>=12: o=0 (zero rows), bo=0 -> st stays 0

        // sincos pair renorm via DPP neighbor exchange
        float p1 = ror16<1>(st);
        float p15 = ror16<15>(st);
        float pv = use_r1 ? p1 : p15;
        if (donorm) {
            float n = __builtin_amdgcn_sqrtf(__builtin_fmaf(st, st, pv * pv)) + 1e-8f;
            st *= rcp_fast(n);
        }

        if (u == 0 && j < 12) out_ptr[0] = st;
        out_ptr += 12;
        cmd = cmd_next;
    }
}

extern "C" void kernel_launch(void* const* d_in, const int* in_sizes, int n_in,
                              void* d_out, int out_size, void* d_ws, size_t ws_size,
                              hipStream_t stream) {
    const float* init_state = (const float*)d_in[0];
    const float* commands   = (const float*)d_in[1];
    const float* ln_g       = (const float*)d_in[2];
    const float* ln_b       = (const float*)d_in[3];
    const float* W_in       = (const float*)d_in[4];
    const float* b_in       = (const float*)d_in[5];
    const float* W_ih       = (const float*)d_in[6];
    const float* W_hh       = (const float*)d_in[7];
    const float* b_ih       = (const float*)d_in[8];
    const float* b_hh       = (const float*)d_in[9];
    const float* W_out      = (const float*)d_in[10];
    const float* b_out      = (const float*)d_in[11];

    int B = in_sizes[0] / 12;           // 8192
    int T = in_sizes[1] / (B * 4);      // 256

    int blocks = B / 2;                 // 2 batch elements per 64-thread wave
    vm_kernel<<<blocks, 64, 0, stream>>>(init_state, commands, ln_g, ln_b,
                                         W_in, b_in, W_ih, W_hh, b_ih, b_hh,
                                         W_out, b_out, (float*)d_out, B, T);
}